// Round 8
// baseline (1537.851 us; speedup 1.0000x reference)
//
#include <hip/hip_runtime.h>
#include <cmath>

#define T_STEPS 512
#define BATCH   64
#define ISZ     512
#define HSZ     512
#define EXN     32768   // u64 words per ring slot (64 batches x 512)

// ---------------------------------------------------------------------------
// Dual-path tagged-word exchange. One u64 = {tag=t+1 (hi32), h bits (lo32)}.
//  exF (ws[0 .. 2*EXN))     : fast copy, plain store -> producer-XCD L2,
//                             polled with sc0 (L1-bypass) loads. Fast ONLY
//                             when producer+consumer share an XCD (heuristic).
//  exS (ws[2*EXN .. 4*EXN)) : safety copy, agent-scope atomics via MALL --
//                             placement-independent, guarantees progress.
// Consumer accepts a word from EITHER copy with tag==t. Tags strictly
// increase, payload+tag share one u64 -> no stale-accept, no tearing.
// Correctness never depends on WG->XCD mapping (G16); only speed does.
// ---------------------------------------------------------------------------
__device__ __forceinline__ void ld2F(unsigned long long& a, unsigned long long& b,
                                     const unsigned long long* p0,
                                     const unsigned long long* p1) {
    asm volatile("global_load_dwordx2 %0, %2, off sc0\n\t"
                 "global_load_dwordx2 %1, %3, off sc0\n\t"
                 "s_waitcnt vmcnt(0)"
                 : "=&v"(a), "=&v"(b) : "v"(p0), "v"(p1));
}
__device__ __forceinline__ void stF(unsigned long long* p, unsigned long long v) {
    asm volatile("global_store_dwordx2 %0, %1, off" :: "v"(p), "v"(v) : "memory");
}

// Volatile-asm 16B load: pins weight panels (128 floats/thread budget, R6
// post-mortem: 256 aborts RA). Proven harmless R4/R5/R7.
__device__ __forceinline__ float4 ld_pin_f4(const float* p) {
    float4 v;
    asm volatile("global_load_dwordx4 %0, %1, off" : "=v"(v) : "v"(p));
    return v;
}

// ---------------------------------------------------------------------------
// 16-k-segment dot for 4 output rows x 2 batches, merging butterfly over the
// 32 ksegs (lane bits 0..4): 9 shfls. Lane kseg<8 ends with the full dot for
// row=((kseg>>1)&1)+2*((kseg>>2)&1), b=kseg&1. (R4-proven, 1020 us kernel.)
// LDS layout: float4[base + kseg*5 + i] (5-f4 slot pad).
// ---------------------------------------------------------------------------
__device__ __forceinline__ float dot16_fold(const float4 (&W)[4][4],
                                            const float4* __restrict__ src,
                                            int parbase4, int kseg) {
    const float4* s0 = src + parbase4 + kseg * 5;   // batch 0
    const float4* s1 = s0 + 160;                    // batch 1
    float A0 = 0.f, A1 = 0.f, A2 = 0.f, A3 = 0.f;
    float B0 = 0.f, B1 = 0.f, B2 = 0.f, B3 = 0.f;
    #pragma unroll
    for (int i = 0; i < 4; ++i) {
        const float4 h0 = s0[i];
        const float4 h1 = s1[i];
        const float4 w0 = W[0][i], w1 = W[1][i], w2 = W[2][i], w3 = W[3][i];
        A0 = fmaf(w0.x, h0.x, A0); A0 = fmaf(w0.y, h0.y, A0);
        A0 = fmaf(w0.z, h0.z, A0); A0 = fmaf(w0.w, h0.w, A0);
        A1 = fmaf(w1.x, h0.x, A1); A1 = fmaf(w1.y, h0.y, A1);
        A1 = fmaf(w1.z, h0.z, A1); A1 = fmaf(w1.w, h0.w, A1);
        A2 = fmaf(w2.x, h0.x, A2); A2 = fmaf(w2.y, h0.y, A2);
        A2 = fmaf(w2.z, h0.z, A2); A2 = fmaf(w2.w, h0.w, A2);
        A3 = fmaf(w3.x, h0.x, A3); A3 = fmaf(w3.y, h0.y, A3);
        A3 = fmaf(w3.z, h0.z, A3); A3 = fmaf(w3.w, h0.w, A3);
        B0 = fmaf(w0.x, h1.x, B0); B0 = fmaf(w0.y, h1.y, B0);
        B0 = fmaf(w0.z, h1.z, B0); B0 = fmaf(w0.w, h1.w, B0);
        B1 = fmaf(w1.x, h1.x, B1); B1 = fmaf(w1.y, h1.y, B1);
        B1 = fmaf(w1.z, h1.z, B1); B1 = fmaf(w1.w, h1.w, B1);
        B2 = fmaf(w2.x, h1.x, B2); B2 = fmaf(w2.y, h1.y, B2);
        B2 = fmaf(w2.z, h1.z, B2); B2 = fmaf(w2.w, h1.w, B2);
        B3 = fmaf(w3.x, h1.x, B3); B3 = fmaf(w3.y, h1.y, B3);
        B3 = fmaf(w3.z, h1.z, B3); B3 = fmaf(w3.w, h1.w, B3);
    }
    const bool sb0 = (kseg & 1) != 0;
    const bool sb1 = (kseg & 2) != 0;
    const bool sb2 = (kseg & 4) != 0;
    const float u0 = (sb0 ? B0 : A0) + __shfl_xor(sb0 ? A0 : B0, 1, 64);
    const float u1 = (sb0 ? B1 : A1) + __shfl_xor(sb0 ? A1 : B1, 1, 64);
    const float u2 = (sb0 ? B2 : A2) + __shfl_xor(sb0 ? A2 : B2, 1, 64);
    const float u3 = (sb0 ? B3 : A3) + __shfl_xor(sb0 ? A3 : B3, 1, 64);
    const float w01 = (sb1 ? u1 : u0) + __shfl_xor(sb1 ? u0 : u1, 2, 64);
    const float w23 = (sb1 ? u3 : u2) + __shfl_xor(sb1 ? u2 : u3, 2, 64);
    float z = (sb2 ? w23 : w01) + __shfl_xor(sb2 ? w01 : w23, 4, 64);
    z += __shfl_xor(z, 8, 64);
    z += __shfl_xor(z, 16, 64);
    return z;
}

// ---------------------------------------------------------------------------
// Fused RNN: R4's proven 1020us skeleton (256 WGs = 32 pairs x 8 slices,
// 512 thr, 1 WG/CU, thread owns 4 rows x 16 k x 2 batches, weights pinned,
// parity LDS, one barrier/step, in-loop xw) with ONLY the exchange replaced
// by the dual-path (local-L2 fast + MALL safety) protocol. Diagnostics R2/
// R4/R7 proved the step is serialized on exchange propagation, not compute.
// ---------------------------------------------------------------------------
__global__ __launch_bounds__(512, 2) void rnn_fused(const float* __restrict__ x,
                                                    const float* __restrict__ wih,
                                                    const float* __restrict__ whh,
                                                    float* __restrict__ out,
                                                    unsigned long long* __restrict__ ex) {
    __shared__ __align__(16) float hls[2560];   // [2 par][2 b][32 kseg][5 f4]
    __shared__ __align__(16) float xss[2560];   // same layout, x rows
    const float4* hl4 = (const float4*)hls;
    const float4* xs4 = (const float4*)xss;

    const int tid  = threadIdx.x;
    const int bid  = blockIdx.x;
    const int xcd  = bid & 7;             // XCD under round-robin dispatch
    const int ib   = bid >> 3;            // 0..31 within XCD
    const int p    = xcd * 4 + (ib & 3);  // batch pair (all 8 WGs of a pair
    const int g    = ib >> 2;             //  share bid&7 -> co-XCD heuristic)
    const int kseg = tid & 31;
    const int jg   = tid >> 5;
    const int jb   = g * 64 + jg * 4;

    // ---- weight micro-panels: 4 rows x 16 k of W_hh and W_ih (128 f32) ----
    float4 wh[4][4], wi[4][4];
    #pragma unroll
    for (int r = 0; r < 4; ++r) {
        const float* hr = whh + (size_t)(jb + r) * HSZ + kseg * 16;
        const float* ir = wih + (size_t)(jb + r) * ISZ + kseg * 16;
        #pragma unroll
        for (int i = 0; i < 4; ++i) {
            wh[r][i] = ld_pin_f4(hr + 4 * i);
            wi[r][i] = ld_pin_f4(ir + 4 * i);
        }
    }
    asm volatile("s_waitcnt vmcnt(0)" ::: "memory");
    __builtin_amdgcn_sched_barrier(0);

    // exchange pointers: fast copies at +0, safety copies at +2*EXN
    unsigned long long* exf0 = ex + (size_t)(2 * p + 0) * 512 + tid;
    unsigned long long* exf1 = ex + (size_t)(2 * p + 1) * 512 + tid;
    unsigned long long* exs0 = exf0 + 2 * (size_t)EXN;
    unsigned long long* exs1 = exf1 + 2 * (size_t)EXN;

    // hl scatter offset for polled word k=tid (float idx; b=1 adds 640)
    const int whf = (tid >> 4) * 20 + ((tid >> 2) & 3) * 4 + (tid & 3);

    // x staging role: thread covers (bx, io..io+1), coalesced float2
    const int bx = tid >> 8;
    const int io = (tid & 255) * 2;
    const int xf = bx * 640 + (io >> 4) * 20 + ((io >> 2) & 3) * 4 + (io & 3);
    const float* xsrc = x + (size_t)(2 * p + bx) * ISZ + io;

    // designated-lane roles (valid for kseg<8)
    const int row  = ((kseg >> 1) & 1) + 2 * ((kseg >> 2) & 1);
    const int br   = kseg & 1;
    const int outj = jb + row;
    const int outb = 2 * p + br;
    float* outp = out + (size_t)outb * HSZ + outj;                 // + t*B*H
    unsigned long long* exfself = ex + (size_t)outb * 512 + outj;  // + slot*EXN
    unsigned long long* exsself = exfself + 2 * (size_t)EXN;

    // ---- prologue: stage x(0) (par 0), compute xw(0) ----
    {
        const float2 v = *(const float2*)xsrc;
        *(float2*)&xss[xf] = v;
    }
    __syncthreads();
    float xwv = dot16_fold(wi, xs4, 0, kseg);

    for (int t = 0; t < T_STEPS; ++t) {
        const int  parh4 = (t & 1) * 320;          // f4 base for hls
        const bool havex = (t < T_STEPS - 1);

        // issue x(t+1) prefetch early: HBM latency hides under the poll
        float2 xv;
        if (havex) xv = *(const float2*)(xsrc + (size_t)(t + 1) * (BATCH * ISZ));

        if (t > 0) {
            const size_t soff = (size_t)((t - 1) & 1) * EXN;
            const unsigned long long* f0 = exf0 + soff;
            const unsigned long long* f1 = exf1 + soff;
            unsigned long long v0, v1;
            bool ok0 = false, ok1 = false;
            ld2F(v0, v1, f0, f1);                  // first probe, one RT
            ok0 = ((unsigned)(v0 >> 32) == (unsigned)t);
            ok1 = ((unsigned)(v1 >> 32) == (unsigned)t);
            int it = 0;
            while (!(ok0 && ok1)) {
                __builtin_amdgcn_s_sleep(1);       // throttle L2 hammering
                unsigned long long w0, w1;
                ld2F(w0, w1, f0, f1);
                if (!ok0 && (unsigned)(w0 >> 32) == (unsigned)t) { v0 = w0; ok0 = true; }
                if (!ok1 && (unsigned)(w1 >> 32) == (unsigned)t) { v1 = w1; ok1 = true; }
                if ((++it & 3) == 3) {             // placement-independent net
                    if (!ok0) {
                        unsigned long long s = __hip_atomic_load(exs0 + soff,
                            __ATOMIC_RELAXED, __HIP_MEMORY_SCOPE_AGENT);
                        if ((unsigned)(s >> 32) == (unsigned)t) { v0 = s; ok0 = true; }
                    }
                    if (!ok1) {
                        unsigned long long s = __hip_atomic_load(exs1 + soff,
                            __ATOMIC_RELAXED, __HIP_MEMORY_SCOPE_AGENT);
                        if ((unsigned)(s >> 32) == (unsigned)t) { v1 = s; ok1 = true; }
                    }
                }
            }
            union { unsigned u; float f; } c0, c1;
            c0.u = (unsigned)v0; c1.u = (unsigned)v1;
            hls[parh4 * 4 + whf]       = c0.f;     // batch 0
            hls[parh4 * 4 + 640 + whf] = c1.f;     // batch 1
        }
        if (havex) *(float2*)&xss[((t + 1) & 1) * 1280 + xf] = xv;
        __syncthreads();                           // single barrier per step

        float acc = 0.f;
        if (t > 0)
            acc = dot16_fold(wh, hl4, parh4, kseg);

        if (kseg < 8) {                            // 8 designated lanes / 32
            const float a2 = acc + xwv;
            const float e  = __expf(2.f * a2);     // tanh = (e-1)/(e+1)
            const float hv = 1.f - 2.f / (e + 1.f);
            outp[(size_t)t * (BATCH * HSZ)] = hv;
            if (havex) {
                const size_t so = (size_t)(t & 1) * EXN;
                union { float f; unsigned u; } c; c.f = hv;
                const unsigned long long v =
                    ((unsigned long long)(unsigned)(t + 1) << 32) | c.u;
                stF(exfself + so, v);              // fast: local-XCD L2 first
                __hip_atomic_store(exsself + so, v, __ATOMIC_RELAXED,
                                   __HIP_MEMORY_SCOPE_AGENT);  // safety: MALL
            } else {
                out[(size_t)T_STEPS * BATCH * HSZ + (size_t)outb * HSZ + outj] = hv;
            }
        }

        // xw(t+1): independent of the exchange -> fills the propagation window
        if (havex)
            xwv = dot16_fold(wi, xs4, ((t + 1) & 1) * 320, kseg);
    }
}

// ---------------------------------------------------------------------------
extern "C" void kernel_launch(void* const* d_in, const int* in_sizes, int n_in,
                              void* d_out, int out_size, void* d_ws, size_t ws_size,
                              hipStream_t stream) {
    (void)in_sizes; (void)n_in; (void)out_size; (void)ws_size;
    const float* x   = (const float*)d_in[0];   // (512,64,512)
    const float* wih = (const float*)d_in[1];   // (512,512)
    const float* whh = (const float*)d_in[2];   // (512,512)
    float*       out = (float*)d_out;           // h_all (T,B,H) ++ h_last (B,H)
    unsigned long long* ex = (unsigned long long*)d_ws;   // 4*EXN u64 = 1 MB

    // zero BOTH exchange regions (fast + safety); harness poisons d_ws.
    (void)hipMemsetAsync(d_ws, 0, 4 * EXN * sizeof(unsigned long long), stream);

    hipLaunchKernelGGL(rnn_fused, dim3(256), dim3(512), 0, stream,
                       x, wih, whh, out, ex);
}

// Round 9
// 1417.691 us; speedup vs baseline: 1.0848x; 1.0848x over previous
//
#include <hip/hip_runtime.h>
#include <cmath>

#define T_STEPS 512
#define BATCH   64
#define ISZ     512
#define HSZ     512
#define EXN     32768   // u64 words per ring slot (64 batches x 512)

// ---------------------------------------------------------------------------
// Tagged-word exchange (proven protocol): one atomic u64 = {tag=t+1, h bits}.
// R8 lesson: agent-scope atomic store + tight relaxed-atomic poll IS the
// fastest visible path; plain-store "fast paths" are not promptly visible.
// ---------------------------------------------------------------------------
__device__ __forceinline__ void ex_store(unsigned long long* w, float h, unsigned tag) {
    union { float f; unsigned u; } c; c.f = h;
    const unsigned long long v = ((unsigned long long)tag << 32) | (unsigned long long)c.u;
    __hip_atomic_store(w, v, __ATOMIC_RELAXED, __HIP_MEMORY_SCOPE_AGENT);
}

// Volatile-asm 16B load: pins weight panels (128 floats/thread budget; R6
// post-mortem: 256 aborts RA). Proven harmless R4/R5/R7/R8.
__device__ __forceinline__ float4 ld_pin_f4(const float* p) {
    float4 v;
    asm volatile("global_load_dwordx4 %0, %1, off" : "=v"(v) : "v"(p));
    return v;
}

// ---------------------------------------------------------------------------
// Single-batch 16-k-segment dot for 4 output rows, merging butterfly over the
// 32 ksegs (lane bits 0..4): 6 shfls. Lane kseg<4 ends with the full dot for
// row = kseg&3 (2-level merge proven in R4's dot16_fold; this is its
// single-batch half). src layout: float4[base + kseg*5 + i] (5-f4 slot pad,
// identical addresses to the R4 kernel's proven layout).
// ---------------------------------------------------------------------------
__device__ __forceinline__ float dot4_fold(const float4 (&W)[4][4],
                                           const float4* __restrict__ src,
                                           int base4, int kseg) {
    const float4* s = src + base4 + kseg * 5;
    float a0 = 0.f, a1 = 0.f, a2 = 0.f, a3 = 0.f;
    #pragma unroll
    for (int i = 0; i < 4; ++i) {
        const float4 h = s[i];
        const float4 w0 = W[0][i], w1 = W[1][i], w2 = W[2][i], w3 = W[3][i];
        a0 = fmaf(w0.x, h.x, a0); a0 = fmaf(w0.y, h.y, a0);
        a0 = fmaf(w0.z, h.z, a0); a0 = fmaf(w0.w, h.w, a0);
        a1 = fmaf(w1.x, h.x, a1); a1 = fmaf(w1.y, h.y, a1);
        a1 = fmaf(w1.z, h.z, a1); a1 = fmaf(w1.w, h.w, a1);
        a2 = fmaf(w2.x, h.x, a2); a2 = fmaf(w2.y, h.y, a2);
        a2 = fmaf(w2.z, h.z, a2); a2 = fmaf(w2.w, h.w, a2);
        a3 = fmaf(w3.x, h.x, a3); a3 = fmaf(w3.y, h.y, a3);
        a3 = fmaf(w3.z, h.z, a3); a3 = fmaf(w3.w, h.w, a3);
    }
    const bool sb0 = (kseg & 1) != 0;   // row bit 0
    const bool sb1 = (kseg & 2) != 0;   // row bit 1
    const float u0 = (sb0 ? a1 : a0) + __shfl_xor(sb0 ? a0 : a1, 1, 64);
    const float u1 = (sb0 ? a3 : a2) + __shfl_xor(sb0 ? a2 : a3, 1, 64);
    float z = (sb1 ? u1 : u0) + __shfl_xor(sb1 ? u0 : u1, 2, 64);
    z += __shfl_xor(z, 4, 64);
    z += __shfl_xor(z, 8, 64);
    z += __shfl_xor(z, 16, 64);
    return z;
}

// ---------------------------------------------------------------------------
// Fused RNN, R4 skeleton with BATCH-SPLIT PIPELINING. 256 WGs = 32 pairs x
// 8 slices, 512 thr, 1 WG/CU; thread owns 4 rows x 16 k x 2 batches; weights
// pinned (128 f32). Each step = two sub-iterations (batch 0, batch 1):
//   poll b -> stage -> barrier -> hh-dot b -> tanh/store/ex_store b -> xw b
// The two batches are INDEPENDENT recurrences, so each batch's store->poll
// propagation window grows from ~400 cyc (R4: exposed ~full latency) to
// ~half a step: fixed point S = 2C + 2*max(0, L - S/2) -> S ~ L + C.
// Per-step DS work <= R4 (16 f4 reads + 24 shfl; no R5-style doubling);
// LDS addresses byte-identical to R4's proven layout; per-word tagged-ring
// induction applies per-batch verbatim (b0/b1 chains are independent).
// ---------------------------------------------------------------------------
__global__ __launch_bounds__(512, 2) void rnn_fused(const float* __restrict__ x,
                                                    const float* __restrict__ wih,
                                                    const float* __restrict__ whh,
                                                    float* __restrict__ out,
                                                    unsigned long long* __restrict__ ex) {
    __shared__ __align__(16) float hls[2560];   // [2 par][2 b][32 kseg][5 f4]
    __shared__ __align__(16) float xss[2560];   // same layout, x rows
    const float4* hl4 = (const float4*)hls;
    const float4* xs4 = (const float4*)xss;

    const int tid  = threadIdx.x;
    const int bid  = blockIdx.x;
    const int xcd  = bid & 7;             // XCD under round-robin dispatch
    const int ib   = bid >> 3;            // 0..31 within XCD
    const int p    = xcd * 4 + (ib & 3);  // batch pair (8 WGs co-XCD heuristic)
    const int g    = ib >> 2;             // neuron slice 0..7
    const int kseg = tid & 31;            // 16-wide k segment
    const int jg   = tid >> 5;            // 0..15 -> 4 j rows each
    const int jb   = g * 64 + jg * 4;

    // ---- weight micro-panels: 4 rows x 16 k of W_hh and W_ih (128 f32) ----
    float4 wh[4][4], wi[4][4];
    #pragma unroll
    for (int r = 0; r < 4; ++r) {
        const float* hr = whh + (size_t)(jb + r) * HSZ + kseg * 16;
        const float* ir = wih + (size_t)(jb + r) * ISZ + kseg * 16;
        #pragma unroll
        for (int i = 0; i < 4; ++i) {
            wh[r][i] = ld_pin_f4(hr + 4 * i);
            wi[r][i] = ld_pin_f4(ir + 4 * i);
        }
    }
    asm volatile("s_waitcnt vmcnt(0)" ::: "memory");
    __builtin_amdgcn_sched_barrier(0);

    // poll pointers: word k=tid of each batch of this pair
    unsigned long long* exw0 = ex + (size_t)(2 * p + 0) * 512 + tid;
    unsigned long long* exw1 = ex + (size_t)(2 * p + 1) * 512 + tid;

    // hl scatter offset for polled word k=tid (float idx; b=1 adds 640)
    const int whf = (tid >> 4) * 20 + ((tid >> 2) & 3) * 4 + (tid & 3);

    // x staging role: thread covers (bx, io..io+1), coalesced float2
    const int bx = tid >> 8;
    const int io = (tid & 255) * 2;
    const int xf = bx * 640 + (io >> 4) * 20 + ((io >> 2) & 3) * 4 + (io & 3);
    const float* xsrc = x + (size_t)(2 * p + bx) * ISZ + io;

    // designated-lane roles (valid for kseg<4: row = kseg)
    const int outj = jb + (kseg & 3);
    const int ob0  = 2 * p;
    const int ob1  = 2 * p + 1;
    float* outp0 = out + (size_t)ob0 * HSZ + outj;                // + t*B*H
    float* outp1 = out + (size_t)ob1 * HSZ + outj;
    unsigned long long* exs0 = ex + (size_t)ob0 * 512 + outj;     // + slot*EXN
    unsigned long long* exs1 = ex + (size_t)ob1 * 512 + outj;

    // ---- prologue: stage x(0) (par 0), compute xw(0) for both batches ----
    {
        const float2 v = *(const float2*)xsrc;
        *(float2*)&xss[xf] = v;
    }
    __syncthreads();
    float xw0 = dot4_fold(wi, xs4, 0,   kseg);
    float xw1 = dot4_fold(wi, xs4, 160, kseg);

    for (int t = 0; t < T_STEPS; ++t) {
        const int  parh4 = (t & 1) * 320;          // f4 base for hls
        const bool havex = (t < T_STEPS - 1);
        const size_t soff = (size_t)((t - 1) & 1) * EXN;

        // issue x(t+1) prefetch early: HBM latency hides under sub-A's poll
        float2 xv;
        if (havex) xv = *(const float2*)(xsrc + (size_t)(t + 1) * (BATCH * ISZ));

        // ==================== sub-iteration A: batch 0 ====================
        if (t > 0) {
            unsigned long long v = __hip_atomic_load(exw0 + soff, __ATOMIC_RELAXED,
                                                     __HIP_MEMORY_SCOPE_AGENT);
            while ((unsigned)(v >> 32) != (unsigned)t) {
                __builtin_amdgcn_s_sleep(1);
                v = __hip_atomic_load(exw0 + soff, __ATOMIC_RELAXED,
                                      __HIP_MEMORY_SCOPE_AGENT);
            }
            union { unsigned u; float f; } c; c.u = (unsigned)v;
            hls[parh4 * 4 + whf] = c.f;            // batch 0, parity t
        }
        if (havex) *(float2*)&xss[((t + 1) & 1) * 1280 + xf] = xv;
        __syncthreads();                           // barrier A

        {
            float acc = 0.f;
            if (t > 0) acc = dot4_fold(wh, hl4, parh4, kseg);
            if (kseg < 4) {
                const float a2 = acc + xw0;
                const float e  = __expf(2.f * a2);     // tanh=(e-1)/(e+1)
                const float hv = 1.f - 2.f / (e + 1.f);
                outp0[(size_t)t * (BATCH * HSZ)] = hv;
                if (havex)
                    ex_store(exs0 + (size_t)(t & 1) * EXN, hv, (unsigned)(t + 1));
                else
                    out[(size_t)T_STEPS * BATCH * HSZ + (size_t)ob0 * HSZ + outj] = hv;
            }
        }
        // xw b0 (t+1): off-chain, widens b0's store-propagation window
        if (havex) xw0 = dot4_fold(wi, xs4, ((t + 1) & 1) * 320, kseg);

        // ==================== sub-iteration B: batch 1 ====================
        if (t > 0) {
            unsigned long long v = __hip_atomic_load(exw1 + soff, __ATOMIC_RELAXED,
                                                     __HIP_MEMORY_SCOPE_AGENT);
            while ((unsigned)(v >> 32) != (unsigned)t) {
                __builtin_amdgcn_s_sleep(1);
                v = __hip_atomic_load(exw1 + soff, __ATOMIC_RELAXED,
                                      __HIP_MEMORY_SCOPE_AGENT);
            }
            union { unsigned u; float f; } c; c.u = (unsigned)v;
            hls[parh4 * 4 + 640 + whf] = c.f;      // batch 1, parity t
        }
        __syncthreads();                           // barrier B

        {
            float acc = 0.f;
            if (t > 0) acc = dot4_fold(wh, hl4, parh4 + 160, kseg);
            if (kseg < 4) {
                const float a2 = acc + xw1;
                const float e  = __expf(2.f * a2);
                const float hv = 1.f - 2.f / (e + 1.f);
                outp1[(size_t)t * (BATCH * HSZ)] = hv;
                if (havex)
                    ex_store(exs1 + (size_t)(t & 1) * EXN, hv, (unsigned)(t + 1));
                else
                    out[(size_t)T_STEPS * BATCH * HSZ + (size_t)ob1 * HSZ + outj] = hv;
            }
        }
        // xw b1 (t+1): off-chain, widens b1's store-propagation window
        if (havex) xw1 = dot4_fold(wi, xs4, ((t + 1) & 1) * 320 + 160, kseg);
    }
}

// ---------------------------------------------------------------------------
extern "C" void kernel_launch(void* const* d_in, const int* in_sizes, int n_in,
                              void* d_out, int out_size, void* d_ws, size_t ws_size,
                              hipStream_t stream) {
    (void)in_sizes; (void)n_in; (void)out_size; (void)ws_size;
    const float* x   = (const float*)d_in[0];   // (512,64,512)
    const float* wih = (const float*)d_in[1];   // (512,512)
    const float* whh = (const float*)d_in[2];   // (512,512)
    float*       out = (float*)d_out;           // h_all (T,B,H) ++ h_last (B,H)
    unsigned long long* ex = (unsigned long long*)d_ws;   // 2*EXN u64 = 512 KB

    // zero the exchange tags (harness poisons d_ws each launch)
    (void)hipMemsetAsync(d_ws, 0, 2 * EXN * sizeof(unsigned long long), stream);

    hipLaunchKernelGGL(rnn_fused, dim3(256), dim3(512), 0, stream,
                       x, wih, whh, out, ex);
}